// Round 15
// baseline (119.526 us; speedup 1.0000x reference)
//
#include <hip/hip_runtime.h>
#include <stdint.h>

#define DM 1024     // D_MODEL
#define NH 16       // NUM_HEADS
#define DK 64       // D_K

typedef __attribute__((ext_vector_type(8))) __bf16 bf16x8;
typedef __attribute__((ext_vector_type(4))) float f32x4;

__device__ __forceinline__ float bf2f(unsigned short u) {
    union { uint32_t i; float f; } x; x.i = ((uint32_t)u) << 16; return x.f;
}
__device__ __forceinline__ unsigned short f2bf(float f) {
    union { float f; uint32_t i; } x; x.f = f;
    uint32_t r = x.i + 0x7fffu + ((x.i >> 16) & 1u);   // RNE
    return (unsigned short)(r >> 16);
}

__device__ __forceinline__ void gl2lds16(const void* g, void* l) {
    __builtin_amdgcn_global_load_lds(
        (const __attribute__((address_space(1))) void*)g,
        (__attribute__((address_space(3))) void*)l, 16, 0, 0);
}

__device__ __forceinline__ f32x4 mfma_bf16(bf16x8 a, bf16x8 b, f32x4 c) {
    return __builtin_amdgcn_mfma_f32_16x16x32_bf16(a, b, c, 0, 0, 0);
}

template<int N> __device__ __forceinline__ void waitvm() {
    if constexpr (N == 0) asm volatile("s_waitcnt vmcnt(0)" ::: "memory");
}

// ---------------------------------------------------------------------------
// fp32 -> bf16 conversion, 3 segments of exactly 1M floats (weights only).
// Round-15: q/k/v conversion moved INTO the QKV GEMM via fp32 LDS staging
// (gload_lds of raw fp32 + transient cvt between ds_read and MFMA -- no
// persistent registers, unlike the r12/r13 spill disasters).
// ---------------------------------------------------------------------------
struct CvtArgs {
    const float* src[3];
    unsigned short* dst[3];
};

__global__ __launch_bounds__(256) void cvt3(CvtArgs a) {
    const int t = blockIdx.x * 256 + threadIdx.x;
    const int seg = t >> 18;
    const int off = t & 0x3ffff;
    const float4 v = reinterpret_cast<const float4*>(a.src[seg])[off];
    ushort4 o;
    o.x = f2bf(v.x); o.y = f2bf(v.y); o.z = f2bf(v.z); o.w = f2bf(v.w);
    reinterpret_cast<ushort4*>(a.dst[seg])[off] = o;
}

// ---------------------------------------------------------------------------
// Unified NT GEMM: C[z][M,N] = A[z] @ W[z]^T + bias[z]
// BMxBN tile, BK=32, 256 threads = 4 waves (2x2), per-wave (BM/2)x(BN/2).
// Ring-2 double buffer; stage 1 tile ahead via global_load_lds; vmcnt(0)+
// barrier per tile. rowSplit selects per-batch W/bias. XCD swizzle.
// F32A=true (QKV): A staged as RAW FP32 via gload_lds (16KB/tile buffer);
//   fragments are ds_read as 2x float4 and converted to bf16 transiently
//   (fuse_w's proven ld_cvt8 pattern -- nothing persistent, no spill
//   surface). A-tile swizzle: rows are 128B -> read byte ^= (l15&7)<<4
//   (2-way max after swizzle = free); write side = pre-swizzled global
//   source k-offset ((tid&7)^((tid>>3)&7))*4, LDS dest linear (rule 21).
// F32A=false (final GEMM): bf16 gload_lds path (r5-r9 swizzle pair).
// Both out dtypes use the LDS-staged coalesced epilogue.
// ---------------------------------------------------------------------------
template<typename OutT>
struct GKArgs {
    const void* A[3];
    const unsigned short* Wlo[3];
    const unsigned short* Whi[3];
    const float* blo[3];
    const float* bhi[3];
    OutT* C[3];
};

template<int BM, int BN, bool F32A, typename OutT>
__global__ __launch_bounds__(256, 3) void gemmk(GKArgs<OutT> g, int M, int N, int K,
                                                int nwgx, int rowSplit)
{
    static_assert(!F32A || BM == 128, "F32A staging hardcodes BM=128");
    constexpr int SB = BN / 64;           // B stage-issues per tile
    constexpr int FN = BN / 32;           // B frags per wave
    // ring buffer size in ushorts: A region + B region
    constexpr int ABYTES = F32A ? BM * 128 : BM * 64;   // fp32 vs bf16 A
    constexpr int BUFE   = ABYTES / 2 + BN * 32;
    constexpr int EPIE   = BM * BN * (int)(sizeof(OutT) / 2);
    constexpr int LDSE   = (2 * BUFE > EPIE) ? 2 * BUFE : EPIE;

    const int z = blockIdx.y;
    const int nwg = gridDim.x;
    const int f = blockIdx.x;
    const int q = nwg >> 3;                       // nwg % 8 == 0
    const int f2 = (f & 7) * q + (f >> 3);        // XCD-contiguous chunks
    const int bx = f2 % nwgx, by = f2 / nwgx;
    const int row0 = by * BM, col0 = bx * BN;

    const bool hi = row0 >= rowSplit;
    const unsigned short* __restrict__ Bw = hi ? g.Whi[z] : g.Wlo[z];
    const float* __restrict__ bias = hi ? g.bhi[z] : g.blo[z];
    OutT* __restrict__ C = g.C[z];

    __shared__ unsigned short lds[LDSE];

    const int tid  = threadIdx.x;
    const int lane = tid & 63;
    const int w    = tid >> 6;          // wave 0..3
    const int wr   = w >> 1, wc = w & 1;
    const int l15  = lane & 15;
    const int swz  = (l15 & 12) << 2;   // bf16-tile read-side byte XOR

    // B: lane-permuted global source, linear LDS dest (gload_lds path)
    const int tidp = tid ^ ((tid >> 4) & 3);
    const unsigned short* bSrc = Bw + (size_t)(col0 + (tidp >> 2)) * K + (tidp & 3) * 8;

    // A sources
    const float* aSrcF = nullptr;
    const unsigned short* aSrcH = nullptr;
    if constexpr (F32A)
        // pre-swizzled k-offset: LDS slot (tid&7)*16B within a 128B row holds
        // global k-bytes ((tid&7)^(row&7))*16, row = tid>>3 within each issue
        aSrcF = (const float*)g.A[z]
              + (size_t)(row0 + (tid >> 3)) * K
              + (size_t)(((tid & 7) ^ ((tid >> 3) & 7)) * 4);
    else
        aSrcH = (const unsigned short*)g.A[z] + (size_t)(row0 + (tidp >> 2)) * K + (tidp & 3) * 8;

    // fragment read bases
    // fp32 A: byte = row*128 + (lane>>4)*32, swizzled by (l15&7)<<4 (+ m*2048)
    const int aB0f = (((wr * 64 + l15) * 128) + (lane >> 4) * 32) ^ ((l15 & 7) << 4);
    // bf16 A: byte = row*64 + (lane>>4)*16, swizzled by swz (+ m*1024)
    const int aB0h = (((wr * 64 + l15) * 64) + (lane >> 4) * 16) ^ swz;
    const int bBase = (((wc * (BN / 2) + l15) * 64) + (lane >> 4) * 16) ^ swz;   // + n*1024

    f32x4 acc[4][FN];
    #pragma unroll
    for (int m = 0; m < 4; ++m)
        #pragma unroll
        for (int n = 0; n < FN; ++n)
            acc[m][n] = (f32x4){0.f, 0.f, 0.f, 0.f};

    const int NT = K >> 5;   // 32 tiles for K=1024

    #define STAGE(t) do { \
        unsigned short* bufE = lds + ((t) & 1) * BUFE; \
        if constexpr (F32A) { \
            _Pragma("unroll") \
            for (int i_ = 0; i_ < 4; ++i_) \
                gl2lds16(aSrcF + (size_t)(t) * 32 + (size_t)i_ * 32 * K, \
                         bufE + i_ * 2048 + tid * 8); \
        } else { \
            _Pragma("unroll") \
            for (int i_ = 0; i_ < BM / 64; ++i_) \
                gl2lds16(aSrcH + (size_t)(t) * 32 + (size_t)i_ * 64 * K, \
                         bufE + i_ * 2048 + tid * 8); \
        } \
        _Pragma("unroll") \
        for (int i_ = 0; i_ < SB; ++i_) \
            gl2lds16(bSrc + (size_t)(t) * 32 + (size_t)i_ * 64 * K, \
                     bufE + ABYTES / 2 + i_ * 2048 + tid * 8); \
    } while (0)

    // prologue: stage tile 0, drain, barrier
    STAGE(0);
    waitvm<0>();
    __builtin_amdgcn_s_barrier();

    #pragma unroll 2
    for (int t = 0; t < NT; ++t) {
        if (t + 1 < NT) STAGE(t + 1);
        const char* LAb = (const char*)lds + (t & 1) * (BUFE * 2);
        const char* LBb = LAb + ABYTES;
        bf16x8 af[4], bfv[FN];
        if constexpr (F32A) {
            #pragma unroll
            for (int m = 0; m < 4; ++m) {
                const int b0 = m * 2048 + aB0f;
                const float4 f0 = *reinterpret_cast<const float4*>(LAb + b0);
                const float4 f1 = *reinterpret_cast<const float4*>(LAb + (b0 ^ 16));
                union { unsigned short u[8]; bf16x8 v; } r_;
                r_.u[0] = f2bf(f0.x); r_.u[1] = f2bf(f0.y);
                r_.u[2] = f2bf(f0.z); r_.u[3] = f2bf(f0.w);
                r_.u[4] = f2bf(f1.x); r_.u[5] = f2bf(f1.y);
                r_.u[6] = f2bf(f1.z); r_.u[7] = f2bf(f1.w);
                af[m] = r_.v;
            }
        } else {
            #pragma unroll
            for (int m = 0; m < 4; ++m)
                af[m] = *reinterpret_cast<const bf16x8*>(LAb + m * 1024 + aB0h);
        }
        #pragma unroll
        for (int n = 0; n < FN; ++n)
            bfv[n] = *reinterpret_cast<const bf16x8*>(LBb + n * 1024 + bBase);
        __builtin_amdgcn_s_setprio(1);
        #pragma unroll
        for (int m = 0; m < 4; ++m)
            #pragma unroll
            for (int n = 0; n < FN; ++n)
                acc[m][n] = mfma_bf16(af[m], bfv[n], acc[m][n]);
        __builtin_amdgcn_s_setprio(0);
        if (t + 1 < NT) waitvm<0>();   // next tile's stages complete
        __builtin_amdgcn_s_barrier();
    }
    #undef STAGE

    // ---- epilogue: C/D layout col=lane&15, row=(lane>>4)*4+reg
    // LDS-staged coalesced store for BOTH dtypes.
    const int cr = (lane >> 4) * 4, cc = l15;
    if constexpr (sizeof(OutT) == 2) {
        unsigned short* CE = lds;                  // [BM rows][BN cols] bf16
        #pragma unroll
        for (int n = 0; n < FN; ++n) {
            const int col = wc * (BN / 2) + n * 16 + cc;
            const float bv = bias[col0 + col];
            #pragma unroll
            for (int m = 0; m < 4; ++m) {
                const int rowb = wr * 64 + m * 16 + cr;
                #pragma unroll
                for (int r = 0; r < 4; ++r)
                    CE[(rowb + r) * BN + col] = f2bf(acc[m][n][r] + bv);
            }
        }
        __syncthreads();
        constexpr int NJ = BM * BN * 2 / 4096;     // 4KB per iteration
        #pragma unroll
        for (int j = 0; j < NJ; ++j) {
            const int off = j * 4096 + tid * 16;   // byte offset
            const int row = off / (BN * 2);
            const int cole = (off % (BN * 2)) >> 1;
            *reinterpret_cast<uint4*>(&C[(size_t)(row0 + row) * N + col0 + cole]) =
                *reinterpret_cast<const uint4*>((const char*)CE + off);
        }
    } else {
        float* CE = reinterpret_cast<float*>(lds); // [BM rows][BN cols] fp32
        #pragma unroll
        for (int n = 0; n < FN; ++n) {
            const int col = wc * (BN / 2) + n * 16 + cc;
            const float bv = bias[col0 + col];
            #pragma unroll
            for (int m = 0; m < 4; ++m) {
                const int rowb = wr * 64 + m * 16 + cr;
                #pragma unroll
                for (int r = 0; r < 4; ++r)
                    CE[(rowb + r) * BN + col] = acc[m][n][r] + bv;
            }
        }
        __syncthreads();
        constexpr int NJ = BM * BN * 4 / 4096;     // 4KB per iteration
        #pragma unroll
        for (int j = 0; j < NJ; ++j) {
            const int off = j * 4096 + tid * 16;   // byte offset
            const int row = off / (BN * 4);
            const int cole = (off % (BN * 4)) >> 2;
            *reinterpret_cast<uint4*>(&C[(size_t)(row0 + row) * N + col0 + cole]) =
                *reinterpret_cast<const uint4*>((const char*)CE + off);
        }
    }
}

// ---------------------------------------------------------------------------
// K^T V partials per (b,h) over an s-chunk (bf16 in, fp32 accum/out).
// float4 (b128) LDS access (r14).
// ---------------------------------------------------------------------------
__global__ __launch_bounds__(256) void ktv_partial(
    const unsigned short* __restrict__ Kb, const unsigned short* __restrict__ Vb,
    const int* __restrict__ mask, float* __restrict__ Mpart,
    float* __restrict__ cvpart, int S, int schunk)
{
    __shared__ float Ks[16][64];
    __shared__ float Vs[16][64];
    __shared__ float cvs[16][64];
    const int bh = blockIdx.x, chunk = blockIdx.y, BH = gridDim.x;
    const int b = bh >> 4, h = bh & 15;
    const int tid = threadIdx.x;
    const int tx = tid & 15, ty = tid >> 4;
    const int s0 = chunk * schunk;

    float acc[4][4] = {};
    float cv[4] = {0.f, 0.f, 0.f, 0.f};

    for (int sc = 0; sc < schunk; sc += 16) {
        const int s = s0 + sc + ty;
        const size_t rowoff = (size_t)(b * S + s) * DM + h * DK + tx * 4;
        const ushort4 kraw = *reinterpret_cast<const ushort4*>(Kb + rowoff);
        const ushort4 vraw = *reinterpret_cast<const ushort4*>(Vb + rowoff);
        float4 kv = make_float4(bf2f(kraw.x), bf2f(kraw.y), bf2f(kraw.z), bf2f(kraw.w));
        const float4 vv = make_float4(bf2f(vraw.x), bf2f(vraw.y), bf2f(vraw.z), bf2f(vraw.w));
        if (mask[b * S + s] == 0) {
            cv[0] += vv.x; cv[1] += vv.y; cv[2] += vv.z; cv[3] += vv.w;
            kv = make_float4(0.f, 0.f, 0.f, 0.f);
        }
        __syncthreads();
        *reinterpret_cast<float4*>(&Ks[ty][tx * 4]) = kv;
        *reinterpret_cast<float4*>(&Vs[ty][tx * 4]) = vv;
        __syncthreads();
        #pragma unroll
        for (int ss = 0; ss < 16; ++ss) {
            const float4 kq = *reinterpret_cast<const float4*>(&Ks[ss][ty * 4]);
            const float4 vq = *reinterpret_cast<const float4*>(&Vs[ss][tx * 4]);
            const float kvv[4] = {kq.x, kq.y, kq.z, kq.w};
            const float vvv[4] = {vq.x, vq.y, vq.z, vq.w};
            #pragma unroll
            for (int i = 0; i < 4; ++i)
                #pragma unroll
                for (int j = 0; j < 4; ++j)
                    acc[i][j] += kvv[i] * vvv[j];
        }
    }

    const size_t mbase = ((size_t)chunk * BH + bh) * (DK * DK);
    #pragma unroll
    for (int i = 0; i < 4; ++i)
        #pragma unroll
        for (int j = 0; j < 4; ++j)
            Mpart[mbase + (size_t)(ty * 4 + i) * DK + tx * 4 + j] = acc[i][j];

    __syncthreads();
    #pragma unroll
    for (int j = 0; j < 4; ++j) cvs[ty][tx * 4 + j] = cv[j];
    __syncthreads();
    if (tid < DK) {
        float s = 0.f;
        #pragma unroll
        for (int r = 0; r < 16; ++r) s += cvs[r][tid];
        cvpart[((size_t)chunk * BH + bh) * DK + tid] = s;
    }
}

// ---------------------------------------------------------------------------
// Reduce partials: Mm[bh] = sum_c Mpart[c,bh] * (1/sqrt(DK)); cvec likewise.
// ---------------------------------------------------------------------------
__global__ __launch_bounds__(256) void reduce_m(
    const float* __restrict__ Mpart, const float* __restrict__ cvpart,
    float* __restrict__ Mm, float* __restrict__ cvec, int nchunk, int BH)
{
    const int bh = blockIdx.x;
    const int tid = threadIdx.x;
    const int e0 = blockIdx.y * 512;
    for (int e = e0 + tid; e < e0 + 512; e += 256) {
        float s = 0.f;
        for (int c = 0; c < nchunk; ++c)
            s += Mpart[((size_t)c * BH + bh) * (DK * DK) + e];
        Mm[(size_t)bh * DK * DK + e] = s * 0.125f;   // 1/sqrt(64)
    }
    if (blockIdx.y == 0 && tid < DK) {
        float s = 0.f;
        for (int c = 0; c < nchunk; ++c)
            s += cvpart[((size_t)c * BH + bh) * DK + tid];
        cvec[bh * DK + tid] = s;
    }
}

// ---------------------------------------------------------------------------
// Wf[b][o][h*64+d] = sum_e Mm[b,h,d,e] * Wo[o, h*64+e]   (bf16 out)
// ---------------------------------------------------------------------------
__device__ __forceinline__ bf16x8 ld_cvt8(const float* p) {
    const float4 x = *reinterpret_cast<const float4*>(p);
    const float4 y = *reinterpret_cast<const float4*>(p + 4);
    union { unsigned short u[8]; bf16x8 v; } r;
    r.u[0] = f2bf(x.x); r.u[1] = f2bf(x.y); r.u[2] = f2bf(x.z); r.u[3] = f2bf(x.w);
    r.u[4] = f2bf(y.x); r.u[5] = f2bf(y.y); r.u[6] = f2bf(y.z); r.u[7] = f2bf(y.w);
    return r.v;
}

__global__ __launch_bounds__(256) void fuse_w(
    const float* __restrict__ Mm, const float* __restrict__ Wo,
    unsigned short* __restrict__ Wf)
{
    const int h = blockIdx.y;
    const int b = blockIdx.z;
    const int o0 = blockIdx.x * 256;
    const int tid = threadIdx.x, lane = tid & 63, w = tid >> 6;
    const int l15 = lane & 15, q8 = (lane >> 4) * 8;
    const float* MmH = Mm + (size_t)(b * NH + h) * (DK * DK);

    f32x4 acc[4][4];
    #pragma unroll
    for (int m = 0; m < 4; ++m)
        #pragma unroll
        for (int n = 0; n < 4; ++n)
            acc[m][n] = (f32x4){0.f, 0.f, 0.f, 0.f};

    bf16x8 af[4][2], bf[4][2];
    #pragma unroll
    for (int m = 0; m < 4; ++m) {
        const int orow = o0 + w * 64 + m * 16 + l15;
        #pragma unroll
        for (int kk = 0; kk < 2; ++kk)
            af[m][kk] = ld_cvt8(Wo + (size_t)orow * DM + h * DK + kk * 32 + q8);
    }
    #pragma unroll
    for (int n = 0; n < 4; ++n) {
        const int d = n * 16 + l15;
        #pragma unroll
        for (int kk = 0; kk < 2; ++kk)
            bf[n][kk] = ld_cvt8(MmH + (size_t)d * DK + kk * 32 + q8);
    }
    #pragma unroll
    for (int kk = 0; kk < 2; ++kk)
        #pragma unroll
        for (int m = 0; m < 4; ++m)
            #pragma unroll
            for (int n = 0; n < 4; ++n)
                acc[m][n] = mfma_bf16(af[m][kk], bf[n][kk], acc[m][n]);

    const int cr = (lane >> 4) * 4, cc = lane & 15;
    #pragma unroll
    for (int n = 0; n < 4; ++n)
        #pragma unroll
        for (int m = 0; m < 4; ++m)
            #pragma unroll
            for (int r = 0; r < 4; ++r)
                Wf[(size_t)b * DM * DM +
                   (size_t)(o0 + w * 64 + m * 16 + cr + r) * DM +
                   h * DK + n * 16 + cc] = f2bf(acc[m][n][r]);
}

// ---------------------------------------------------------------------------
// bias2[b][o] = bo[o] - 1e9 * sum_j cvec[b*1024 + j] * Wo[o, j]
// Wave-per-o GEMV: one Wo-row read serves both batches.
// ---------------------------------------------------------------------------
__global__ __launch_bounds__(256) void fuse_bias(
    const float* __restrict__ cvec, const float* __restrict__ Wo,
    const float* __restrict__ bo, float* __restrict__ bias2)
{
    const int w = threadIdx.x >> 6, lane = threadIdx.x & 63;
    const int o = blockIdx.x * 4 + w;
    const float* wr = Wo + (size_t)o * DM + lane * 16;
    const float* c0 = cvec + lane * 16;
    const float* c1 = cvec + DM + lane * 16;
    float s0 = 0.f, s1 = 0.f;
    #pragma unroll
    for (int u = 0; u < 4; ++u) {
        const float4 w4 = *reinterpret_cast<const float4*>(wr + u * 4);
        const float4 a4 = *reinterpret_cast<const float4*>(c0 + u * 4);
        const float4 b4 = *reinterpret_cast<const float4*>(c1 + u * 4);
        s0 += w4.x * a4.x + w4.y * a4.y + w4.z * a4.z + w4.w * a4.w;
        s1 += w4.x * b4.x + w4.y * b4.y + w4.z * b4.z + w4.w * b4.w;
    }
    #pragma unroll
    for (int d = 32; d >= 1; d >>= 1) {
        s0 += __shfl_xor(s0, d, 64);
        s1 += __shfl_xor(s1, d, 64);
    }
    if (lane == 0) {
        const float bv = bo[o];
        bias2[o]      = bv - 1.0e9f * s0;
        bias2[DM + o] = bv - 1.0e9f * s1;
    }
}

// ---------------------------------------------------------------------------
extern "C" void kernel_launch(void* const* d_in, const int* in_sizes, int n_in,
                              void* d_out, int out_size, void* d_ws, size_t ws_size,
                              hipStream_t stream)
{
    const float* q    = (const float*)d_in[0];
    const float* k    = (const float*)d_in[1];
    const float* v    = (const float*)d_in[2];
    const int*   mask = (const int*)  d_in[3];
    const float* Wq   = (const float*)d_in[4];
    const float* bq   = (const float*)d_in[5];
    const float* Wk   = (const float*)d_in[6];
    const float* bk   = (const float*)d_in[7];
    const float* Wv   = (const float*)d_in[8];
    const float* bv   = (const float*)d_in[9];
    const float* Wo   = (const float*)d_in[10];
    const float* bo   = (const float*)d_in[11];
    float* out = (float*)d_out;

    const int BS = in_sizes[0] / DM;   // B*S = 4096
    const int B  = 2;
    const int S  = BS / B;             // 2048
    const int BH = B * NH;             // 32
    const int SCHUNK = 64;
    const int NCHUNK = S / SCHUNK;     // 32
    const size_t BSDM = (size_t)BS * DM;   // 4M
    const size_t DMDM = (size_t)DM * DM;   // 1M

    unsigned short* ws = (unsigned short*)d_ws;
    unsigned short* Wqb = ws;                  // weight bf16 copies (3 x 1M)
    unsigned short* Wkb = Wqb + DMDM;
    unsigned short* Wvb = Wkb + DMDM;
    unsigned short* Qp  = Wvb + DMDM;          // projection outputs (bf16)
    unsigned short* Kp  = Qp + BSDM;
    unsigned short* Vp  = Kp + BSDM;
    float* Mpart = (float*)(Vp + BSDM);        // NCHUNK*BH*DK*DK = 4M floats
    float* cvprt = Mpart + (size_t)NCHUNK * BH * DK * DK;  // 64K floats
    float* Mm    = cvprt + (size_t)NCHUNK * BH * DK;       // 128K floats
    float* cvec  = Mm + (size_t)BH * DK * DK;              // 2K floats
    float* bias2 = cvec + (size_t)B * DM;                  // 2K floats
    unsigned short* Wf = (unsigned short*)Mpart;  // alias: Mpart dead after reduce_m

    const dim3 blk(256);

    // fp32 -> bf16: weights only (Wq, Wk, Wv)
    CvtArgs cv;
    cv.src[0] = Wq; cv.dst[0] = Wqb;
    cv.src[1] = Wk; cv.dst[1] = Wkb;
    cv.src[2] = Wv; cv.dst[2] = Wvb;
    cvt3<<<dim3(3 * 1024), blk, 0, stream>>>(cv);

    // batched QKV projections: fp32-A staged through LDS, 128^2 tiles,
    // grid (256, 3) = 768 blocks
    GKArgs<unsigned short> ga;
    ga.A[0] = q;   ga.A[1] = k;   ga.A[2] = v;
    ga.Wlo[0] = ga.Whi[0] = Wqb;
    ga.Wlo[1] = ga.Whi[1] = Wkb;
    ga.Wlo[2] = ga.Whi[2] = Wvb;
    ga.blo[0] = ga.bhi[0] = bq;
    ga.blo[1] = ga.bhi[1] = bk;
    ga.blo[2] = ga.bhi[2] = bv;
    ga.C[0] = Qp;  ga.C[1] = Kp;  ga.C[2] = Vp;
    gemmk<128, 128, true, unsigned short>
        <<<dim3((DM / 128) * (BS / 128), 3), blk, 0, stream>>>(
        ga, BS, DM, DM, DM / 128, 1 << 30);

    // per-head K^T V partials + reduction
    ktv_partial<<<dim3(BH, NCHUNK), blk, 0, stream>>>(Kp, Vp, mask, Mpart, cvprt, S, SCHUNK);
    reduce_m<<<dim3(BH, 8), blk, 0, stream>>>(Mpart, cvprt, Mm, cvec, NCHUNK, BH);

    // fold Mm into Wo (per batch) + fold mask-correction into bias
    fuse_w<<<dim3(DM / 256, NH, B), blk, 0, stream>>>(Mm, Wo, Wf);
    fuse_bias<<<dim3(DM / 4), blk, 0, stream>>>(cvec, Wo, bo, bias2);

    // out = Qp @ Wf[b]^T + bias2[b]: bf16-A path, 128x64 tiles -> 512 blocks
    GKArgs<float> gf;
    gf.A[0] = Qp;
    gf.Wlo[0] = Wf;        gf.Whi[0] = Wf + DMDM;
    gf.blo[0] = bias2;     gf.bhi[0] = bias2 + DM;
    gf.C[0] = out;
    gf.A[1] = gf.A[2] = nullptr;
    gf.Wlo[1] = gf.Wlo[2] = gf.Whi[1] = gf.Whi[2] = nullptr;
    gf.blo[1] = gf.blo[2] = gf.bhi[1] = gf.bhi[2] = nullptr;
    gf.C[1] = gf.C[2] = nullptr;
    gemmk<128, 64, false, float>
        <<<dim3((DM / 64) * (BS / 128), 1), blk, 0, stream>>>(
        gf, BS, DM, DM, DM / 64, S);
}

// Round 16
// 118.537 us; speedup vs baseline: 1.0083x; 1.0083x over previous
//
#include <hip/hip_runtime.h>
#include <stdint.h>

#define DM 1024     // D_MODEL
#define NH 16       // NUM_HEADS
#define DK 64       // D_K

typedef __attribute__((ext_vector_type(8))) __bf16 bf16x8;
typedef __attribute__((ext_vector_type(4))) float f32x4;

__device__ __forceinline__ float bf2f(unsigned short u) {
    union { uint32_t i; float f; } x; x.i = ((uint32_t)u) << 16; return x.f;
}
__device__ __forceinline__ unsigned short f2bf(float f) {
    union { float f; uint32_t i; } x; x.f = f;
    uint32_t r = x.i + 0x7fffu + ((x.i >> 16) & 1u);   // RNE
    return (unsigned short)(r >> 16);
}

__device__ __forceinline__ void gl2lds16(const void* g, void* l) {
    __builtin_amdgcn_global_load_lds(
        (const __attribute__((address_space(1))) void*)g,
        (__attribute__((address_space(3))) void*)l, 16, 0, 0);
}

__device__ __forceinline__ f32x4 mfma_bf16(bf16x8 a, bf16x8 b, f32x4 c) {
    return __builtin_amdgcn_mfma_f32_16x16x32_bf16(a, b, c, 0, 0, 0);
}

template<int N> __device__ __forceinline__ void waitvm() {
    if constexpr (N == 0) asm volatile("s_waitcnt vmcnt(0)" ::: "memory");
}

// ---------------------------------------------------------------------------
// fp32 -> bf16 conversion, 15 segments of exactly 1M floats (2^18 float4).
// Final configuration: the separate cvt pass is optimal -- all three
// in-GEMM conversion-fusion attempts (r12 reg-lambdas: spill; r13 named
// scalars: spill; r15 fp32-LDS-staging: +23us on the MFMA critical path)
// were neutral or regressive. This pass runs at HBM roofline (~14us).
// ---------------------------------------------------------------------------
struct CvtArgs {
    const float* src[15];
    unsigned short* dst[15];
};

__global__ __launch_bounds__(256) void cvt15(CvtArgs a) {
    const int t = blockIdx.x * 256 + threadIdx.x;
    const int seg = t >> 18;
    const int off = t & 0x3ffff;
    const float4 v = reinterpret_cast<const float4*>(a.src[seg])[off];
    ushort4 o;
    o.x = f2bf(v.x); o.y = f2bf(v.y); o.z = f2bf(v.z); o.w = f2bf(v.w);
    reinterpret_cast<ushort4*>(a.dst[seg])[off] = o;
}

// ---------------------------------------------------------------------------
// Unified NT GEMM: C[z][M,N] = A[z] @ W[z]^T + bias[z]
// BMxBN tile, BK=32, 256 threads = 4 waves (2x2), per-wave (BM/2)x(BN/2).
// Ring-2 double buffer; stage 1 tile ahead via global_load_lds; vmcnt(0)+
// barrier per tile (m97 pattern; drain hidden by co-resident blocks, m114).
// rowSplit selects per-batch W/bias. XCD-aware block swizzle (nwg % 8 == 0).
// BOTH output dtypes use the LDS-staged coalesced epilogue. Swizzle pair
// (verified r5-r9): write side = lane-permuted global src (tid^((tid>>4)&3)),
// read side = byte XOR (l15&12)<<2.  [Round-10/14 best configuration.]
// ---------------------------------------------------------------------------
template<typename OutT>
struct GKArgs {
    const unsigned short* A[3];
    const unsigned short* Wlo[3];
    const unsigned short* Whi[3];
    const float* blo[3];
    const float* bhi[3];
    OutT* C[3];
};

template<int BM, int BN, typename OutT>
__global__ __launch_bounds__(256, 4) void gemmk(GKArgs<OutT> g, int M, int N, int K,
                                                int nwgx, int rowSplit)
{
    constexpr int SA = BM / 64;          // A stage-issues per tile
    constexpr int SB = BN / 64;          // B stage-issues per tile
    constexpr int FN = BN / 32;          // B frags per wave
    constexpr int BUFE = (BM + BN) * 32; // elements per ring buffer
    constexpr int EPIE = BM * BN * (int)(sizeof(OutT) / 2);
    constexpr int LDSE = (2 * BUFE > EPIE) ? 2 * BUFE : EPIE;

    const int z = blockIdx.y;
    const int nwg = gridDim.x;
    const int f = blockIdx.x;
    const int q = nwg >> 3;                       // nwg % 8 == 0
    const int f2 = (f & 7) * q + (f >> 3);        // XCD-contiguous chunks
    const int bx = f2 % nwgx, by = f2 / nwgx;
    const int row0 = by * BM, col0 = bx * BN;

    const unsigned short* __restrict__ A = g.A[z];
    const bool hi = row0 >= rowSplit;
    const unsigned short* __restrict__ Bw = hi ? g.Whi[z] : g.Wlo[z];
    const float* __restrict__ bias = hi ? g.bhi[z] : g.blo[z];
    OutT* __restrict__ C = g.C[z];

    __shared__ unsigned short lds[LDSE];

    const int tid  = threadIdx.x;
    const int lane = tid & 63;
    const int w    = tid >> 6;          // wave 0..3
    const int wr   = w >> 1, wc = w & 1;
    const int l15  = lane & 15;
    const int swz  = (l15 & 12) << 2;   // read-side byte XOR (bits 5:4)

    // write-side: lane-permuted global source, linear LDS dest
    const int tidp = tid ^ ((tid >> 4) & 3);
    const unsigned short* aSrc = A  + (size_t)(row0 + (tidp >> 2)) * K + (tidp & 3) * 8;
    const unsigned short* bSrc = Bw + (size_t)(col0 + (tidp >> 2)) * K + (tidp & 3) * 8;

    const int aBase = (((wr * 64 + l15) * 64) + (lane >> 4) * 16) ^ swz;         // + m*1024
    const int bBase = (((wc * (BN / 2) + l15) * 64) + (lane >> 4) * 16) ^ swz;   // + n*1024

    f32x4 acc[4][FN];
    #pragma unroll
    for (int m = 0; m < 4; ++m)
        #pragma unroll
        for (int n = 0; n < FN; ++n)
            acc[m][n] = (f32x4){0.f, 0.f, 0.f, 0.f};

    const int NT = K >> 5;   // 32 tiles for K=1024

    #define STAGE(t) do { \
        unsigned short* bufE = lds + ((t) & 1) * BUFE; \
        _Pragma("unroll") \
        for (int i = 0; i < SA; ++i) \
            gl2lds16(aSrc + (size_t)(t) * 32 + (size_t)i * 64 * K, \
                     bufE + i * 2048 + tid * 8); \
        _Pragma("unroll") \
        for (int i = 0; i < SB; ++i) \
            gl2lds16(bSrc + (size_t)(t) * 32 + (size_t)i * 64 * K, \
                     bufE + BM * 32 + i * 2048 + tid * 8); \
    } while (0)

    // prologue: stage tile 0, drain, barrier
    STAGE(0);
    waitvm<0>();
    __builtin_amdgcn_s_barrier();

    #pragma unroll 2
    for (int t = 0; t < NT; ++t) {
        if (t + 1 < NT) STAGE(t + 1);
        const char* LA = (const char*)lds + (t & 1) * (BUFE * 2);
        const char* LB = LA + BM * 64;
        bf16x8 af[4], bfv[FN];
        #pragma unroll
        for (int m = 0; m < 4; ++m)
            af[m] = *reinterpret_cast<const bf16x8*>(LA + m * 1024 + aBase);
        #pragma unroll
        for (int n = 0; n < FN; ++n)
            bfv[n] = *reinterpret_cast<const bf16x8*>(LB + n * 1024 + bBase);
        __builtin_amdgcn_s_setprio(1);
        #pragma unroll
        for (int m = 0; m < 4; ++m)
            #pragma unroll
            for (int n = 0; n < FN; ++n)
                acc[m][n] = mfma_bf16(af[m], bfv[n], acc[m][n]);
        __builtin_amdgcn_s_setprio(0);
        if (t + 1 < NT) waitvm<0>();   // next tile's stages complete
        __builtin_amdgcn_s_barrier();
    }
    #undef STAGE

    // ---- epilogue: C/D layout col=lane&15, row=(lane>>4)*4+reg
    // LDS-staged coalesced store for BOTH dtypes.
    const int cr = (lane >> 4) * 4, cc = l15;
    if constexpr (sizeof(OutT) == 2) {
        unsigned short* CE = lds;                  // [BM rows][BN cols] bf16
        #pragma unroll
        for (int n = 0; n < FN; ++n) {
            const int col = wc * (BN / 2) + n * 16 + cc;
            const float bv = bias[col0 + col];
            #pragma unroll
            for (int m = 0; m < 4; ++m) {
                const int rowb = wr * 64 + m * 16 + cr;
                #pragma unroll
                for (int r = 0; r < 4; ++r)
                    CE[(rowb + r) * BN + col] = f2bf(acc[m][n][r] + bv);
            }
        }
        __syncthreads();
        constexpr int NJ = BM * BN * 2 / 4096;     // 4KB per iteration
        #pragma unroll
        for (int j = 0; j < NJ; ++j) {
            const int off = j * 4096 + tid * 16;   // byte offset
            const int row = off / (BN * 2);
            const int cole = (off % (BN * 2)) >> 1;
            *reinterpret_cast<uint4*>(&C[(size_t)(row0 + row) * N + col0 + cole]) =
                *reinterpret_cast<const uint4*>((const char*)CE + off);
        }
    } else {
        float* CE = reinterpret_cast<float*>(lds); // [BM rows][BN cols] fp32
        #pragma unroll
        for (int n = 0; n < FN; ++n) {
            const int col = wc * (BN / 2) + n * 16 + cc;
            const float bv = bias[col0 + col];
            #pragma unroll
            for (int m = 0; m < 4; ++m) {
                const int rowb = wr * 64 + m * 16 + cr;
                #pragma unroll
                for (int r = 0; r < 4; ++r)
                    CE[(rowb + r) * BN + col] = acc[m][n][r] + bv;
            }
        }
        __syncthreads();
        constexpr int NJ = BM * BN * 4 / 4096;     // 4KB per iteration
        #pragma unroll
        for (int j = 0; j < NJ; ++j) {
            const int off = j * 4096 + tid * 16;   // byte offset
            const int row = off / (BN * 4);
            const int cole = (off % (BN * 4)) >> 2;
            *reinterpret_cast<uint4*>(&C[(size_t)(row0 + row) * N + col0 + cole]) =
                *reinterpret_cast<const uint4*>((const char*)CE + off);
        }
    }
}

// ---------------------------------------------------------------------------
// K^T V partials per (b,h) over an s-chunk (bf16 in, fp32 accum/out).
// float4 (b128) LDS access (r14).
// ---------------------------------------------------------------------------
__global__ __launch_bounds__(256) void ktv_partial(
    const unsigned short* __restrict__ Kb, const unsigned short* __restrict__ Vb,
    const int* __restrict__ mask, float* __restrict__ Mpart,
    float* __restrict__ cvpart, int S, int schunk)
{
    __shared__ float Ks[16][64];
    __shared__ float Vs[16][64];
    __shared__ float cvs[16][64];
    const int bh = blockIdx.x, chunk = blockIdx.y, BH = gridDim.x;
    const int b = bh >> 4, h = bh & 15;
    const int tid = threadIdx.x;
    const int tx = tid & 15, ty = tid >> 4;
    const int s0 = chunk * schunk;

    float acc[4][4] = {};
    float cv[4] = {0.f, 0.f, 0.f, 0.f};

    for (int sc = 0; sc < schunk; sc += 16) {
        const int s = s0 + sc + ty;
        const size_t rowoff = (size_t)(b * S + s) * DM + h * DK + tx * 4;
        const ushort4 kraw = *reinterpret_cast<const ushort4*>(Kb + rowoff);
        const ushort4 vraw = *reinterpret_cast<const ushort4*>(Vb + rowoff);
        float4 kv = make_float4(bf2f(kraw.x), bf2f(kraw.y), bf2f(kraw.z), bf2f(kraw.w));
        const float4 vv = make_float4(bf2f(vraw.x), bf2f(vraw.y), bf2f(vraw.z), bf2f(vraw.w));
        if (mask[b * S + s] == 0) {
            cv[0] += vv.x; cv[1] += vv.y; cv[2] += vv.z; cv[3] += vv.w;
            kv = make_float4(0.f, 0.f, 0.f, 0.f);
        }
        __syncthreads();
        *reinterpret_cast<float4*>(&Ks[ty][tx * 4]) = kv;
        *reinterpret_cast<float4*>(&Vs[ty][tx * 4]) = vv;
        __syncthreads();
        #pragma unroll
        for (int ss = 0; ss < 16; ++ss) {
            const float4 kq = *reinterpret_cast<const float4*>(&Ks[ss][ty * 4]);
            const float4 vq = *reinterpret_cast<const float4*>(&Vs[ss][tx * 4]);
            const float kvv[4] = {kq.x, kq.y, kq.z, kq.w};
            const float vvv[4] = {vq.x, vq.y, vq.z, vq.w};
            #pragma unroll
            for (int i = 0; i < 4; ++i)
                #pragma unroll
                for (int j = 0; j < 4; ++j)
                    acc[i][j] += kvv[i] * vvv[j];
        }
    }

    const size_t mbase = ((size_t)chunk * BH + bh) * (DK * DK);
    #pragma unroll
    for (int i = 0; i < 4; ++i)
        #pragma unroll
        for (int j = 0; j < 4; ++j)
            Mpart[mbase + (size_t)(ty * 4 + i) * DK + tx * 4 + j] = acc[i][j];

    __syncthreads();
    #pragma unroll
    for (int j = 0; j < 4; ++j) cvs[ty][tx * 4 + j] = cv[j];
    __syncthreads();
    if (tid < DK) {
        float s = 0.f;
        #pragma unroll
        for (int r = 0; r < 16; ++r) s += cvs[r][tid];
        cvpart[((size_t)chunk * BH + bh) * DK + tid] = s;
    }
}

// ---------------------------------------------------------------------------
// Reduce partials: Mm[bh] = sum_c Mpart[c,bh] * (1/sqrt(DK)); cvec likewise.
// ---------------------------------------------------------------------------
__global__ __launch_bounds__(256) void reduce_m(
    const float* __restrict__ Mpart, const float* __restrict__ cvpart,
    float* __restrict__ Mm, float* __restrict__ cvec, int nchunk, int BH)
{
    const int bh = blockIdx.x;
    const int tid = threadIdx.x;
    const int e0 = blockIdx.y * 512;
    for (int e = e0 + tid; e < e0 + 512; e += 256) {
        float s = 0.f;
        for (int c = 0; c < nchunk; ++c)
            s += Mpart[((size_t)c * BH + bh) * (DK * DK) + e];
        Mm[(size_t)bh * DK * DK + e] = s * 0.125f;   // 1/sqrt(64)
    }
    if (blockIdx.y == 0 && tid < DK) {
        float s = 0.f;
        for (int c = 0; c < nchunk; ++c)
            s += cvpart[((size_t)c * BH + bh) * DK + tid];
        cvec[bh * DK + tid] = s;
    }
}

// ---------------------------------------------------------------------------
// Wf[b][o][h*64+d] = sum_e Mm[b,h,d,e] * Wo[o, h*64+e]   (bf16 out)
// ---------------------------------------------------------------------------
__device__ __forceinline__ bf16x8 ld_cvt8(const float* p) {
    const float4 x = *reinterpret_cast<const float4*>(p);
    const float4 y = *reinterpret_cast<const float4*>(p + 4);
    union { unsigned short u[8]; bf16x8 v; } r;
    r.u[0] = f2bf(x.x); r.u[1] = f2bf(x.y); r.u[2] = f2bf(x.z); r.u[3] = f2bf(x.w);
    r.u[4] = f2bf(y.x); r.u[5] = f2bf(y.y); r.u[6] = f2bf(y.z); r.u[7] = f2bf(y.w);
    return r.v;
}

__global__ __launch_bounds__(256) void fuse_w(
    const float* __restrict__ Mm, const float* __restrict__ Wo,
    unsigned short* __restrict__ Wf)
{
    const int h = blockIdx.y;
    const int b = blockIdx.z;
    const int o0 = blockIdx.x * 256;
    const int tid = threadIdx.x, lane = tid & 63, w = tid >> 6;
    const int l15 = lane & 15, q8 = (lane >> 4) * 8;
    const float* MmH = Mm + (size_t)(b * NH + h) * (DK * DK);

    f32x4 acc[4][4];
    #pragma unroll
    for (int m = 0; m < 4; ++m)
        #pragma unroll
        for (int n = 0; n < 4; ++n)
            acc[m][n] = (f32x4){0.f, 0.f, 0.f, 0.f};

    bf16x8 af[4][2], bf[4][2];
    #pragma unroll
    for (int m = 0; m < 4; ++m) {
        const int orow = o0 + w * 64 + m * 16 + l15;
        #pragma unroll
        for (int kk = 0; kk < 2; ++kk)
            af[m][kk] = ld_cvt8(Wo + (size_t)orow * DM + h * DK + kk * 32 + q8);
    }
    #pragma unroll
    for (int n = 0; n < 4; ++n) {
        const int d = n * 16 + l15;
        #pragma unroll
        for (int kk = 0; kk < 2; ++kk)
            bf[n][kk] = ld_cvt8(MmH + (size_t)d * DK + kk * 32 + q8);
    }
    #pragma unroll
    for (int kk = 0; kk < 2; ++kk)
        #pragma unroll
        for (int m = 0; m < 4; ++m)
            #pragma unroll
            for (int n = 0; n < 4; ++n)
                acc[m][n] = mfma_bf16(af[m][kk], bf[n][kk], acc[m][n]);

    const int cr = (lane >> 4) * 4, cc = lane & 15;
    #pragma unroll
    for (int n = 0; n < 4; ++n)
        #pragma unroll
        for (int m = 0; m < 4; ++m)
            #pragma unroll
            for (int r = 0; r < 4; ++r)
                Wf[(size_t)b * DM * DM +
                   (size_t)(o0 + w * 64 + m * 16 + cr + r) * DM +
                   h * DK + n * 16 + cc] = f2bf(acc[m][n][r]);
}

// ---------------------------------------------------------------------------
// bias2[b][o] = bo[o] - 1e9 * sum_j cvec[b*1024 + j] * Wo[o, j]
// Wave-per-o GEMV: one Wo-row read serves both batches.
// ---------------------------------------------------------------------------
__global__ __launch_bounds__(256) void fuse_bias(
    const float* __restrict__ cvec, const float* __restrict__ Wo,
    const float* __restrict__ bo, float* __restrict__ bias2)
{
    const int w = threadIdx.x >> 6, lane = threadIdx.x & 63;
    const int o = blockIdx.x * 4 + w;
    const float* wr = Wo + (size_t)o * DM + lane * 16;
    const float* c0 = cvec + lane * 16;
    const float* c1 = cvec + DM + lane * 16;
    float s0 = 0.f, s1 = 0.f;
    #pragma unroll
    for (int u = 0; u < 4; ++u) {
        const float4 w4 = *reinterpret_cast<const float4*>(wr + u * 4);
        const float4 a4 = *reinterpret_cast<const float4*>(c0 + u * 4);
        const float4 b4 = *reinterpret_cast<const float4*>(c1 + u * 4);
        s0 += w4.x * a4.x + w4.y * a4.y + w4.z * a4.z + w4.w * a4.w;
        s1 += w4.x * b4.x + w4.y * b4.y + w4.z * b4.z + w4.w * b4.w;
    }
    #pragma unroll
    for (int d = 32; d >= 1; d >>= 1) {
        s0 += __shfl_xor(s0, d, 64);
        s1 += __shfl_xor(s1, d, 64);
    }
    if (lane == 0) {
        const float bv = bo[o];
        bias2[o]      = bv - 1.0e9f * s0;
        bias2[DM + o] = bv - 1.0e9f * s1;
    }
}

// ---------------------------------------------------------------------------
extern "C" void kernel_launch(void* const* d_in, const int* in_sizes, int n_in,
                              void* d_out, int out_size, void* d_ws, size_t ws_size,
                              hipStream_t stream)
{
    const float* q    = (const float*)d_in[0];
    const float* k    = (const float*)d_in[1];
    const float* v    = (const float*)d_in[2];
    const int*   mask = (const int*)  d_in[3];
    const float* Wq   = (const float*)d_in[4];
    const float* bq   = (const float*)d_in[5];
    const float* Wk   = (const float*)d_in[6];
    const float* bk   = (const float*)d_in[7];
    const float* Wv   = (const float*)d_in[8];
    const float* bv   = (const float*)d_in[9];
    const float* Wo   = (const float*)d_in[10];
    const float* bo   = (const float*)d_in[11];
    float* out = (float*)d_out;

    const int BS = in_sizes[0] / DM;   // B*S = 4096
    const int B  = 2;
    const int S  = BS / B;             // 2048
    const int BH = B * NH;             // 32
    const int SCHUNK = 64;
    const int NCHUNK = S / SCHUNK;     // 32
    const size_t BSDM = (size_t)BS * DM;   // 4M
    const size_t DMDM = (size_t)DM * DM;   // 1M

    unsigned short* ws = (unsigned short*)d_ws;
    unsigned short* qb   = ws;
    unsigned short* kb   = qb  + BSDM;
    unsigned short* vb   = kb  + BSDM;
    unsigned short* Wqb  = vb  + BSDM;
    unsigned short* Wkb  = Wqb + DMDM;
    unsigned short* Wvb  = Wkb + DMDM;
    unsigned short* Qp   = Wvb + DMDM;
    unsigned short* Kp   = Qp  + BSDM;
    unsigned short* Vp   = Kp  + BSDM;
    // aliases (dead after QKV projections):
    float* Mpart = (float*)kb;                 // 4M floats over kb+vb
    float* cvprt = (float*)Wqb;                // 64K floats
    float* Mm    = cvprt + (size_t)NCHUNK * BH * DK;       // 128K floats
    float* cvec  = Mm    + (size_t)BH * DK * DK;           // 2K floats
    unsigned short* Wf = qb;                   // 2M us (2 x 1024 x 1024 bf16)
    float* bias2 = (float*)Wkb;                // 2K floats

    const dim3 blk(256);

    // fp32 -> bf16: q,k,v (12 x 1M) + Wq,Wk,Wv (3 x 1M)
    CvtArgs cv;
    for (int i = 0; i < 4; ++i) { cv.src[0 + i] = q + (size_t)i * DMDM; cv.dst[0 + i] = qb + (size_t)i * DMDM; }
    for (int i = 0; i < 4; ++i) { cv.src[4 + i] = k + (size_t)i * DMDM; cv.dst[4 + i] = kb + (size_t)i * DMDM; }
    for (int i = 0; i < 4; ++i) { cv.src[8 + i] = v + (size_t)i * DMDM; cv.dst[8 + i] = vb + (size_t)i * DMDM; }
    cv.src[12] = Wq; cv.dst[12] = Wqb;
    cv.src[13] = Wk; cv.dst[13] = Wkb;
    cv.src[14] = Wv; cv.dst[14] = Wvb;
    cvt15<<<dim3(15 * 1024), blk, 0, stream>>>(cv);

    // batched QKV projections: 128^2 tiles, ring-2, grid (256, 3)
    GKArgs<unsigned short> ga;
    ga.A[0] = qb;  ga.A[1] = kb;  ga.A[2] = vb;
    ga.Wlo[0] = ga.Whi[0] = Wqb;
    ga.Wlo[1] = ga.Whi[1] = Wkb;
    ga.Wlo[2] = ga.Whi[2] = Wvb;
    ga.blo[0] = ga.bhi[0] = bq;
    ga.blo[1] = ga.bhi[1] = bk;
    ga.blo[2] = ga.bhi[2] = bv;
    ga.C[0] = Qp;  ga.C[1] = Kp;  ga.C[2] = Vp;
    gemmk<128, 128, unsigned short>
        <<<dim3((DM / 128) * (BS / 128), 3), blk, 0, stream>>>(
        ga, BS, DM, DM, DM / 128, 1 << 30);

    // per-head K^T V partials + reduction
    ktv_partial<<<dim3(BH, NCHUNK), blk, 0, stream>>>(Kp, Vp, mask, Mpart, cvprt, S, SCHUNK);
    reduce_m<<<dim3(BH, 8), blk, 0, stream>>>(Mpart, cvprt, Mm, cvec, NCHUNK, BH);

    // fold Mm into Wo (per batch) + fold mask-correction into bias
    fuse_w<<<dim3(DM / 256, NH, B), blk, 0, stream>>>(Mm, Wo, Wf);
    fuse_bias<<<dim3(DM / 4), blk, 0, stream>>>(cvec, Wo, bo, bias2);

    // out = Qp @ Wf[b]^T + bias2[b]: 128x64 tiles -> 512 blocks (2/CU)
    GKArgs<float> gf;
    gf.A[0] = Qp;
    gf.Wlo[0] = Wf;        gf.Whi[0] = Wf + DMDM;
    gf.blo[0] = bias2;     gf.bhi[0] = bias2 + DM;
    gf.C[0] = out;
    gf.A[1] = gf.A[2] = nullptr;
    gf.Wlo[1] = gf.Wlo[2] = gf.Whi[1] = gf.Whi[2] = nullptr;
    gf.blo[1] = gf.blo[2] = gf.bhi[1] = gf.bhi[2] = nullptr;
    gf.C[1] = gf.C[2] = nullptr;
    gemmk<128, 64, float>
        <<<dim3((DM / 64) * (BS / 128), 1), blk, 0, stream>>>(
        gf, BS, DM, DM, DM / 64, S);
}

// Round 17
// 117.351 us; speedup vs baseline: 1.0185x; 1.0101x over previous
//
#include <hip/hip_runtime.h>
#include <stdint.h>

#define DM 1024     // D_MODEL
#define NH 16       // NUM_HEADS
#define DK 64       // D_K

typedef __attribute__((ext_vector_type(8))) __bf16 bf16x8;
typedef __attribute__((ext_vector_type(4))) float f32x4;

__device__ __forceinline__ float bf2f(unsigned short u) {
    union { uint32_t i; float f; } x; x.i = ((uint32_t)u) << 16; return x.f;
}
__device__ __forceinline__ unsigned short f2bf(float f) {
    union { float f; uint32_t i; } x; x.f = f;
    uint32_t r = x.i + 0x7fffu + ((x.i >> 16) & 1u);   // RNE
    return (unsigned short)(r >> 16);
}

__device__ __forceinline__ void gl2lds16(const void* g, void* l) {
    __builtin_amdgcn_global_load_lds(
        (const __attribute__((address_space(1))) void*)g,
        (__attribute__((address_space(3))) void*)l, 16, 0, 0);
}

__device__ __forceinline__ f32x4 mfma_bf16(bf16x8 a, bf16x8 b, f32x4 c) {
    return __builtin_amdgcn_mfma_f32_16x16x32_bf16(a, b, c, 0, 0, 0);
}

template<int N> __device__ __forceinline__ void waitvm() {
    if constexpr (N == 0) asm volatile("s_waitcnt vmcnt(0)" ::: "memory");
}

// ---------------------------------------------------------------------------
// fp32 -> bf16 conversion, 15 segments of exactly 1M floats (2^18 float4).
// The separate cvt pass is optimal -- all three in-GEMM conversion-fusion
// attempts (r12 reg-lambdas: spill; r13 named scalars: spill; r15
// fp32-LDS-staging: +23us on the MFMA critical path) were neutral or
// regressive. This pass runs at HBM roofline (~14us).
// ---------------------------------------------------------------------------
struct CvtArgs {
    const float* src[15];
    unsigned short* dst[15];
};

__global__ __launch_bounds__(256) void cvt15(CvtArgs a) {
    const int t = blockIdx.x * 256 + threadIdx.x;
    const int seg = t >> 18;
    const int off = t & 0x3ffff;
    const float4 v = reinterpret_cast<const float4*>(a.src[seg])[off];
    ushort4 o;
    o.x = f2bf(v.x); o.y = f2bf(v.y); o.z = f2bf(v.z); o.w = f2bf(v.w);
    reinterpret_cast<ushort4*>(a.dst[seg])[off] = o;
}

// ---------------------------------------------------------------------------
// Unified NT GEMM: C[z][M,N] = A[z] @ W[z]^T + bias[z]
// BMxBN tile, BK=32, 256 threads = 4 waves (2x2), per-wave (BM/2)x(BN/2).
// Ring-2 double buffer; stage 1 tile ahead via global_load_lds; vmcnt(0)+
// barrier per tile (m97 pattern; drain hidden by co-resident blocks, m114).
// rowSplit selects per-batch W/bias. XCD-aware block swizzle (nwg % 8 == 0).
// BOTH output dtypes use the LDS-staged coalesced epilogue. Swizzle pair
// (verified r5-r9): write side = lane-permuted global src (tid^((tid>>4)&3)),
// read side = byte XOR (l15&12)<<2.  [Round-10/14/16 best configuration.]
// ---------------------------------------------------------------------------
template<typename OutT>
struct GKArgs {
    const unsigned short* A[3];
    const unsigned short* Wlo[3];
    const unsigned short* Whi[3];
    const float* blo[3];
    const float* bhi[3];
    OutT* C[3];
};

template<int BM, int BN, typename OutT>
__global__ __launch_bounds__(256, 4) void gemmk(GKArgs<OutT> g, int M, int N, int K,
                                                int nwgx, int rowSplit)
{
    constexpr int SA = BM / 64;          // A stage-issues per tile
    constexpr int SB = BN / 64;          // B stage-issues per tile
    constexpr int FN = BN / 32;          // B frags per wave
    constexpr int BUFE = (BM + BN) * 32; // elements per ring buffer
    constexpr int EPIE = BM * BN * (int)(sizeof(OutT) / 2);
    constexpr int LDSE = (2 * BUFE > EPIE) ? 2 * BUFE : EPIE;

    const int z = blockIdx.y;
    const int nwg = gridDim.x;
    const int f = blockIdx.x;
    const int q = nwg >> 3;                       // nwg % 8 == 0
    const int f2 = (f & 7) * q + (f >> 3);        // XCD-contiguous chunks
    const int bx = f2 % nwgx, by = f2 / nwgx;
    const int row0 = by * BM, col0 = bx * BN;

    const unsigned short* __restrict__ A = g.A[z];
    const bool hi = row0 >= rowSplit;
    const unsigned short* __restrict__ Bw = hi ? g.Whi[z] : g.Wlo[z];
    const float* __restrict__ bias = hi ? g.bhi[z] : g.blo[z];
    OutT* __restrict__ C = g.C[z];

    __shared__ unsigned short lds[LDSE];

    const int tid  = threadIdx.x;
    const int lane = tid & 63;
    const int w    = tid >> 6;          // wave 0..3
    const int wr   = w >> 1, wc = w & 1;
    const int l15  = lane & 15;
    const int swz  = (l15 & 12) << 2;   // read-side byte XOR (bits 5:4)

    // write-side: lane-permuted global source, linear LDS dest
    const int tidp = tid ^ ((tid >> 4) & 3);
    const unsigned short* aSrc = A  + (size_t)(row0 + (tidp >> 2)) * K + (tidp & 3) * 8;
    const unsigned short* bSrc = Bw + (size_t)(col0 + (tidp >> 2)) * K + (tidp & 3) * 8;

    const int aBase = (((wr * 64 + l15) * 64) + (lane >> 4) * 16) ^ swz;         // + m*1024
    const int bBase = (((wc * (BN / 2) + l15) * 64) + (lane >> 4) * 16) ^ swz;   // + n*1024

    f32x4 acc[4][FN];
    #pragma unroll
    for (int m = 0; m < 4; ++m)
        #pragma unroll
        for (int n = 0; n < FN; ++n)
            acc[m][n] = (f32x4){0.f, 0.f, 0.f, 0.f};

    const int NT = K >> 5;   // 32 tiles for K=1024

    #define STAGE(t) do { \
        unsigned short* bufE = lds + ((t) & 1) * BUFE; \
        _Pragma("unroll") \
        for (int i = 0; i < SA; ++i) \
            gl2lds16(aSrc + (size_t)(t) * 32 + (size_t)i * 64 * K, \
                     bufE + i * 2048 + tid * 8); \
        _Pragma("unroll") \
        for (int i = 0; i < SB; ++i) \
            gl2lds16(bSrc + (size_t)(t) * 32 + (size_t)i * 64 * K, \
                     bufE + BM * 32 + i * 2048 + tid * 8); \
    } while (0)

    // prologue: stage tile 0, drain, barrier
    STAGE(0);
    waitvm<0>();
    __builtin_amdgcn_s_barrier();

    #pragma unroll 2
    for (int t = 0; t < NT; ++t) {
        if (t + 1 < NT) STAGE(t + 1);
        const char* LA = (const char*)lds + (t & 1) * (BUFE * 2);
        const char* LB = LA + BM * 64;
        bf16x8 af[4], bfv[FN];
        #pragma unroll
        for (int m = 0; m < 4; ++m)
            af[m] = *reinterpret_cast<const bf16x8*>(LA + m * 1024 + aBase);
        #pragma unroll
        for (int n = 0; n < FN; ++n)
            bfv[n] = *reinterpret_cast<const bf16x8*>(LB + n * 1024 + bBase);
        __builtin_amdgcn_s_setprio(1);
        #pragma unroll
        for (int m = 0; m < 4; ++m)
            #pragma unroll
            for (int n = 0; n < FN; ++n)
                acc[m][n] = mfma_bf16(af[m], bfv[n], acc[m][n]);
        __builtin_amdgcn_s_setprio(0);
        if (t + 1 < NT) waitvm<0>();   // next tile's stages complete
        __builtin_amdgcn_s_barrier();
    }
    #undef STAGE

    // ---- epilogue: C/D layout col=lane&15, row=(lane>>4)*4+reg
    // LDS-staged coalesced store for BOTH dtypes.
    const int cr = (lane >> 4) * 4, cc = l15;
    if constexpr (sizeof(OutT) == 2) {
        unsigned short* CE = lds;                  // [BM rows][BN cols] bf16
        #pragma unroll
        for (int n = 0; n < FN; ++n) {
            const int col = wc * (BN / 2) + n * 16 + cc;
            const float bv = bias[col0 + col];
            #pragma unroll
            for (int m = 0; m < 4; ++m) {
                const int rowb = wr * 64 + m * 16 + cr;
                #pragma unroll
                for (int r = 0; r < 4; ++r)
                    CE[(rowb + r) * BN + col] = f2bf(acc[m][n][r] + bv);
            }
        }
        __syncthreads();
        constexpr int NJ = BM * BN * 2 / 4096;     // 4KB per iteration
        #pragma unroll
        for (int j = 0; j < NJ; ++j) {
            const int off = j * 4096 + tid * 16;   // byte offset
            const int row = off / (BN * 2);
            const int cole = (off % (BN * 2)) >> 1;
            *reinterpret_cast<uint4*>(&C[(size_t)(row0 + row) * N + col0 + cole]) =
                *reinterpret_cast<const uint4*>((const char*)CE + off);
        }
    } else {
        float* CE = reinterpret_cast<float*>(lds); // [BM rows][BN cols] fp32
        #pragma unroll
        for (int n = 0; n < FN; ++n) {
            const int col = wc * (BN / 2) + n * 16 + cc;
            const float bv = bias[col0 + col];
            #pragma unroll
            for (int m = 0; m < 4; ++m) {
                const int rowb = wr * 64 + m * 16 + cr;
                #pragma unroll
                for (int r = 0; r < 4; ++r)
                    CE[(rowb + r) * BN + col] = acc[m][n][r] + bv;
            }
        }
        __syncthreads();
        constexpr int NJ = BM * BN * 4 / 4096;     // 4KB per iteration
        #pragma unroll
        for (int j = 0; j < NJ; ++j) {
            const int off = j * 4096 + tid * 16;   // byte offset
            const int row = off / (BN * 4);
            const int cole = (off % (BN * 4)) >> 2;
            *reinterpret_cast<uint4*>(&C[(size_t)(row0 + row) * N + col0 + cole]) =
                *reinterpret_cast<const uint4*>((const char*)CE + off);
        }
    }
}

// ---------------------------------------------------------------------------
// K^T V partials per (b,h) over an s-chunk (bf16 in, fp32 accum/out).
// float4 (b128) LDS access (r14).
// ---------------------------------------------------------------------------
__global__ __launch_bounds__(256) void ktv_partial(
    const unsigned short* __restrict__ Kb, const unsigned short* __restrict__ Vb,
    const int* __restrict__ mask, float* __restrict__ Mpart,
    float* __restrict__ cvpart, int S, int schunk)
{
    __shared__ float Ks[16][64];
    __shared__ float Vs[16][64];
    __shared__ float cvs[16][64];
    const int bh = blockIdx.x, chunk = blockIdx.y, BH = gridDim.x;
    const int b = bh >> 4, h = bh & 15;
    const int tid = threadIdx.x;
    const int tx = tid & 15, ty = tid >> 4;
    const int s0 = chunk * schunk;

    float acc[4][4] = {};
    float cv[4] = {0.f, 0.f, 0.f, 0.f};

    for (int sc = 0; sc < schunk; sc += 16) {
        const int s = s0 + sc + ty;
        const size_t rowoff = (size_t)(b * S + s) * DM + h * DK + tx * 4;
        const ushort4 kraw = *reinterpret_cast<const ushort4*>(Kb + rowoff);
        const ushort4 vraw = *reinterpret_cast<const ushort4*>(Vb + rowoff);
        float4 kv = make_float4(bf2f(kraw.x), bf2f(kraw.y), bf2f(kraw.z), bf2f(kraw.w));
        const float4 vv = make_float4(bf2f(vraw.x), bf2f(vraw.y), bf2f(vraw.z), bf2f(vraw.w));
        if (mask[b * S + s] == 0) {
            cv[0] += vv.x; cv[1] += vv.y; cv[2] += vv.z; cv[3] += vv.w;
            kv = make_float4(0.f, 0.f, 0.f, 0.f);
        }
        __syncthreads();
        *reinterpret_cast<float4*>(&Ks[ty][tx * 4]) = kv;
        *reinterpret_cast<float4*>(&Vs[ty][tx * 4]) = vv;
        __syncthreads();
        #pragma unroll
        for (int ss = 0; ss < 16; ++ss) {
            const float4 kq = *reinterpret_cast<const float4*>(&Ks[ss][ty * 4]);
            const float4 vq = *reinterpret_cast<const float4*>(&Vs[ss][tx * 4]);
            const float kvv[4] = {kq.x, kq.y, kq.z, kq.w};
            const float vvv[4] = {vq.x, vq.y, vq.z, vq.w};
            #pragma unroll
            for (int i = 0; i < 4; ++i)
                #pragma unroll
                for (int j = 0; j < 4; ++j)
                    acc[i][j] += kvv[i] * vvv[j];
        }
    }

    const size_t mbase = ((size_t)chunk * BH + bh) * (DK * DK);
    #pragma unroll
    for (int i = 0; i < 4; ++i)
        #pragma unroll
        for (int j = 0; j < 4; ++j)
            Mpart[mbase + (size_t)(ty * 4 + i) * DK + tx * 4 + j] = acc[i][j];

    __syncthreads();
    #pragma unroll
    for (int j = 0; j < 4; ++j) cvs[ty][tx * 4 + j] = cv[j];
    __syncthreads();
    if (tid < DK) {
        float s = 0.f;
        #pragma unroll
        for (int r = 0; r < 16; ++r) s += cvs[r][tid];
        cvpart[((size_t)chunk * BH + bh) * DK + tid] = s;
    }
}

// ---------------------------------------------------------------------------
// Reduce partials: Mm[bh] = sum_c Mpart[c,bh] * (1/sqrt(DK)); cvec likewise.
// ---------------------------------------------------------------------------
__global__ __launch_bounds__(256) void reduce_m(
    const float* __restrict__ Mpart, const float* __restrict__ cvpart,
    float* __restrict__ Mm, float* __restrict__ cvec, int nchunk, int BH)
{
    const int bh = blockIdx.x;
    const int tid = threadIdx.x;
    const int e0 = blockIdx.y * 512;
    for (int e = e0 + tid; e < e0 + 512; e += 256) {
        float s = 0.f;
        for (int c = 0; c < nchunk; ++c)
            s += Mpart[((size_t)c * BH + bh) * (DK * DK) + e];
        Mm[(size_t)bh * DK * DK + e] = s * 0.125f;   // 1/sqrt(64)
    }
    if (blockIdx.y == 0 && tid < DK) {
        float s = 0.f;
        for (int c = 0; c < nchunk; ++c)
            s += cvpart[((size_t)c * BH + bh) * DK + tid];
        cvec[bh * DK + tid] = s;
    }
}

// ---------------------------------------------------------------------------
// Merged fuse_w + fuse_bias (round-17: one launch instead of two -- the two
// kernels are independent consumers of reduce_m's output).
// blocks [0, NWF):          Wf[b][o][h*64+d] = sum_e Mm[b,h,d,e]*Wo[o,h*64+e]
// blocks [NWF, NWF+256):    bias2[b][o] = bo[o] - 1e9 * <cvec[b], Wo[o,:]>
// ---------------------------------------------------------------------------
__device__ __forceinline__ bf16x8 ld_cvt8(const float* p) {
    const float4 x = *reinterpret_cast<const float4*>(p);
    const float4 y = *reinterpret_cast<const float4*>(p + 4);
    union { unsigned short u[8]; bf16x8 v; } r;
    r.u[0] = f2bf(x.x); r.u[1] = f2bf(x.y); r.u[2] = f2bf(x.z); r.u[3] = f2bf(x.w);
    r.u[4] = f2bf(y.x); r.u[5] = f2bf(y.y); r.u[6] = f2bf(y.z); r.u[7] = f2bf(y.w);
    return r.v;
}

#define NWF (4 * NH * 2)   // fuse_w blocks: (DM/256) x NH x B = 128

__global__ __launch_bounds__(256) void fuse_wb(
    const float* __restrict__ Mm, const float* __restrict__ cvec,
    const float* __restrict__ Wo, const float* __restrict__ bo,
    unsigned short* __restrict__ Wf, float* __restrict__ bias2)
{
    const int blk = blockIdx.x;
    const int tid = threadIdx.x, lane = tid & 63, w = tid >> 6;

    if (blk < NWF) {
        // ---- fuse_w body (grid decomposition: x=blk&3, h=(blk>>2)&15, b=blk>>6)
        const int o0 = (blk & 3) * 256;
        const int h  = (blk >> 2) & 15;
        const int b  = blk >> 6;
        const int l15 = lane & 15, q8 = (lane >> 4) * 8;
        const float* MmH = Mm + (size_t)(b * NH + h) * (DK * DK);

        f32x4 acc[4][4];
        #pragma unroll
        for (int m = 0; m < 4; ++m)
            #pragma unroll
            for (int n = 0; n < 4; ++n)
                acc[m][n] = (f32x4){0.f, 0.f, 0.f, 0.f};

        bf16x8 af[4][2], bf[4][2];
        #pragma unroll
        for (int m = 0; m < 4; ++m) {
            const int orow = o0 + w * 64 + m * 16 + l15;
            #pragma unroll
            for (int kk = 0; kk < 2; ++kk)
                af[m][kk] = ld_cvt8(Wo + (size_t)orow * DM + h * DK + kk * 32 + q8);
        }
        #pragma unroll
        for (int n = 0; n < 4; ++n) {
            const int d = n * 16 + l15;
            #pragma unroll
            for (int kk = 0; kk < 2; ++kk)
                bf[n][kk] = ld_cvt8(MmH + (size_t)d * DK + kk * 32 + q8);
        }
        #pragma unroll
        for (int kk = 0; kk < 2; ++kk)
            #pragma unroll
            for (int m = 0; m < 4; ++m)
                #pragma unroll
                for (int n = 0; n < 4; ++n)
                    acc[m][n] = mfma_bf16(af[m][kk], bf[n][kk], acc[m][n]);

        const int cr = (lane >> 4) * 4, cc = lane & 15;
        #pragma unroll
        for (int n = 0; n < 4; ++n)
            #pragma unroll
            for (int m = 0; m < 4; ++m)
                #pragma unroll
                for (int r = 0; r < 4; ++r)
                    Wf[(size_t)b * DM * DM +
                       (size_t)(o0 + w * 64 + m * 16 + cr + r) * DM +
                       h * DK + n * 16 + cc] = f2bf(acc[m][n][r]);
    } else {
        // ---- fuse_bias body: wave-per-o GEMV, one Wo-row serves both batches
        const int o = (blk - NWF) * 4 + w;
        const float* wrp = Wo + (size_t)o * DM + lane * 16;
        const float* c0 = cvec + lane * 16;
        const float* c1 = cvec + DM + lane * 16;
        float s0 = 0.f, s1 = 0.f;
        #pragma unroll
        for (int u = 0; u < 4; ++u) {
            const float4 w4 = *reinterpret_cast<const float4*>(wrp + u * 4);
            const float4 a4 = *reinterpret_cast<const float4*>(c0 + u * 4);
            const float4 b4 = *reinterpret_cast<const float4*>(c1 + u * 4);
            s0 += w4.x * a4.x + w4.y * a4.y + w4.z * a4.z + w4.w * a4.w;
            s1 += w4.x * b4.x + w4.y * b4.y + w4.z * b4.z + w4.w * b4.w;
        }
        #pragma unroll
        for (int d = 32; d >= 1; d >>= 1) {
            s0 += __shfl_xor(s0, d, 64);
            s1 += __shfl_xor(s1, d, 64);
        }
        if (lane == 0) {
            const float bv = bo[o];
            bias2[o]      = bv - 1.0e9f * s0;
            bias2[DM + o] = bv - 1.0e9f * s1;
        }
    }
}

// ---------------------------------------------------------------------------
extern "C" void kernel_launch(void* const* d_in, const int* in_sizes, int n_in,
                              void* d_out, int out_size, void* d_ws, size_t ws_size,
                              hipStream_t stream)
{
    const float* q    = (const float*)d_in[0];
    const float* k    = (const float*)d_in[1];
    const float* v    = (const float*)d_in[2];
    const int*   mask = (const int*)  d_in[3];
    const float* Wq   = (const float*)d_in[4];
    const float* bq   = (const float*)d_in[5];
    const float* Wk   = (const float*)d_in[6];
    const float* bk   = (const float*)d_in[7];
    const float* Wv   = (const float*)d_in[8];
    const float* bv   = (const float*)d_in[9];
    const float* Wo   = (const float*)d_in[10];
    const float* bo   = (const float*)d_in[11];
    float* out = (float*)d_out;

    const int BS = in_sizes[0] / DM;   // B*S = 4096
    const int B  = 2;
    const int S  = BS / B;             // 2048
    const int BH = B * NH;             // 32
    const int SCHUNK = 64;
    const int NCHUNK = S / SCHUNK;     // 32
    const size_t BSDM = (size_t)BS * DM;   // 4M
    const size_t DMDM = (size_t)DM * DM;   // 1M

    unsigned short* ws = (unsigned short*)d_ws;
    unsigned short* qb   = ws;
    unsigned short* kb   = qb  + BSDM;
    unsigned short* vb   = kb  + BSDM;
    unsigned short* Wqb  = vb  + BSDM;
    unsigned short* Wkb  = Wqb + DMDM;
    unsigned short* Wvb  = Wkb + DMDM;
    unsigned short* Qp   = Wvb + DMDM;
    unsigned short* Kp   = Qp  + BSDM;
    unsigned short* Vp   = Kp  + BSDM;
    // aliases (dead after QKV projections):
    float* Mpart = (float*)kb;                 // 4M floats over kb+vb
    float* cvprt = (float*)Wqb;                // 64K floats
    float* Mm    = cvprt + (size_t)NCHUNK * BH * DK;       // 128K floats
    float* cvec  = Mm    + (size_t)BH * DK * DK;           // 2K floats
    unsigned short* Wf = qb;                   // 2M us (2 x 1024 x 1024 bf16)
    float* bias2 = (float*)Wkb;                // 2K floats

    const dim3 blk(256);

    // fp32 -> bf16: q,k,v (12 x 1M) + Wq,Wk,Wv (3 x 1M)
    CvtArgs cv;
    for (int i = 0; i < 4; ++i) { cv.src[0 + i] = q + (size_t)i * DMDM; cv.dst[0 + i] = qb + (size_t)i * DMDM; }
    for (int i = 0; i < 4; ++i) { cv.src[4 + i] = k + (size_t)i * DMDM; cv.dst[4 + i] = kb + (size_t)i * DMDM; }
    for (int i = 0; i < 4; ++i) { cv.src[8 + i] = v + (size_t)i * DMDM; cv.dst[8 + i] = vb + (size_t)i * DMDM; }
    cv.src[12] = Wq; cv.dst[12] = Wqb;
    cv.src[13] = Wk; cv.dst[13] = Wkb;
    cv.src[14] = Wv; cv.dst[14] = Wvb;
    cvt15<<<dim3(15 * 1024), blk, 0, stream>>>(cv);

    // batched QKV projections: 128^2 tiles, ring-2, grid (256, 3)
    GKArgs<unsigned short> ga;
    ga.A[0] = qb;  ga.A[1] = kb;  ga.A[2] = vb;
    ga.Wlo[0] = ga.Whi[0] = Wqb;
    ga.Wlo[1] = ga.Whi[1] = Wkb;
    ga.Wlo[2] = ga.Whi[2] = Wvb;
    ga.blo[0] = ga.bhi[0] = bq;
    ga.blo[1] = ga.bhi[1] = bk;
    ga.blo[2] = ga.bhi[2] = bv;
    ga.C[0] = Qp;  ga.C[1] = Kp;  ga.C[2] = Vp;
    gemmk<128, 128, unsigned short>
        <<<dim3((DM / 128) * (BS / 128), 3), blk, 0, stream>>>(
        ga, BS, DM, DM, DM / 128, 1 << 30);

    // per-head K^T V partials + reduction
    ktv_partial<<<dim3(BH, NCHUNK), blk, 0, stream>>>(Kp, Vp, mask, Mpart, cvprt, S, SCHUNK);
    reduce_m<<<dim3(BH, 8), blk, 0, stream>>>(Mpart, cvprt, Mm, cvec, NCHUNK, BH);

    // fold Mm into Wo + fold mask-correction into bias (single merged launch)
    fuse_wb<<<dim3(NWF + DM / 4), blk, 0, stream>>>(Mm, cvec, Wo, bo, Wf, bias2);

    // out = Qp @ Wf[b]^T + bias2[b]: 128x64 tiles -> 512 blocks (2/CU)
    GKArgs<float> gf;
    gf.A[0] = Qp;
    gf.Wlo[0] = Wf;        gf.Whi[0] = Wf + DMDM;
    gf.blo[0] = bias2;     gf.bhi[0] = bias2 + DM;
    gf.C[0] = out;
    gf.A[1] = gf.A[2] = nullptr;
    gf.Wlo[1] = gf.Wlo[2] = gf.Whi[1] = gf.Whi[2] = nullptr;
    gf.blo[1] = gf.blo[2] = gf.bhi[1] = gf.bhi[2] = nullptr;
    gf.C[1] = gf.C[2] = nullptr;
    gemmk<128, 64, float>
        <<<dim3((DM / 64) * (BS / 128), 1), blk, 0, stream>>>(
        gf, BS, DM, DM, DM / 64, S);
}